// Round 1
// baseline (311.022 us; speedup 1.0000x reference)
//
#include <hip/hip_runtime.h>

#define B 8
#define L 8
#define E 128
#define NN 1024
#define NODE 256
#define DEP 128
#define FF 384   // NODE + DEP

// ---------------------------------------------------------------------------
// init: out[b,n,0:256] = context[b,n,:], out[b,n,256:384] = 0; zero s and c.
// Works in float4 units. out rows are 384 floats = 96 float4 (64 ctx + 32 zero).
// ---------------------------------------------------------------------------
__global__ __launch_bounds__(256) void init_kernel(const float4* __restrict__ ctx4,
                                                   float4* __restrict__ out4,
                                                   float4* __restrict__ ws4,
                                                   int ws_count4) {
    const float4 z = make_float4(0.f, 0.f, 0.f, 0.f);
    size_t i = (size_t)blockIdx.x * blockDim.x + threadIdx.x;
    size_t stride = (size_t)gridDim.x * blockDim.x;
    const size_t total_out4 = (size_t)B * NN * (FF / 4);   // 786432
    for (size_t idx = i; idx < total_out4; idx += stride) {
        int f4 = (int)(idx % (FF / 4));
        size_t node = idx / (FF / 4);
        out4[idx] = (f4 < NODE / 4) ? ctx4[node * (NODE / 4) + f4] : z;
    }
    for (size_t idx = i; idx < (size_t)ws_count4; idx += stride) ws4[idx] = z;
}

// ---------------------------------------------------------------------------
// edge kernel: one block (128 threads) per edge (b,e) of layer `layer`.
// feat = out[b, tails, :] (384 floats staged in LDS).
// thread d computes msg[d] = dot(W[r][d,:], feat) * m, atomicAdd into s,c.
// ---------------------------------------------------------------------------
__global__ __launch_bounds__(128) void edge_kernel(const float* __restrict__ W,
                                                   const int* __restrict__ heads,
                                                   const int* __restrict__ tails,
                                                   const int* __restrict__ rels,
                                                   const float* __restrict__ mask,
                                                   const float* __restrict__ out,
                                                   float* __restrict__ s,
                                                   float* __restrict__ c,
                                                   int layer) {
    int be = blockIdx.x;          // b*E + e
    int b = be >> 7;              // E = 128
    int e = be & (E - 1);
    int idx = (b * L + layer) * E + e;
    int t = tails[idx];
    int r = rels[idx];
    int h = heads[idx];
    float m = mask[idx];

    __shared__ float fs[FF];
    int tid = threadIdx.x;

    const float4* feat4 = (const float4*)(out + ((size_t)b * NN + t) * FF);
    if (tid < FF / 4) ((float4*)fs)[tid] = feat4[tid];
    __syncthreads();

    if (m != 0.f) {
        const float4* w4 = (const float4*)(W + ((size_t)r * DEP + tid) * FF);
        const float4* f4 = (const float4*)fs;
        float acc = 0.f;
#pragma unroll 8
        for (int k = 0; k < FF / 4; ++k) {
            float4 w = w4[k];
            float4 f = f4[k];
            acc = fmaf(w.x, f.x, acc);
            acc = fmaf(w.y, f.y, acc);
            acc = fmaf(w.z, f.z, acc);
            acc = fmaf(w.w, f.w, acc);
        }
        atomicAdd(&s[((size_t)b * NN + h) * DEP + tid], acc * m);
        if (tid == 0) atomicAdd(&c[(size_t)b * NN + h], m);
    }
}

// ---------------------------------------------------------------------------
// node kernel: one block (128 threads) per node (b,n).
// child = c>0 ? s/max(c,1) : keep; then reset s,c to 0 for the next layer.
// ---------------------------------------------------------------------------
__global__ __launch_bounds__(128) void node_kernel(float* __restrict__ out,
                                                   float* __restrict__ s,
                                                   float* __restrict__ c) {
    int node = blockIdx.x;        // b*NN + n
    int d = threadIdx.x;
    float cv = c[node];
    __syncthreads();              // all lanes read c before lane 0 clears it
    size_t si = (size_t)node * DEP + d;
    float sv = s[si];
    if (cv > 0.f) {
        out[(size_t)node * FF + NODE + d] = sv / fmaxf(cv, 1.f);
    }
    s[si] = 0.f;
    if (d == 0) c[node] = 0.f;
}

extern "C" void kernel_launch(void* const* d_in, const int* in_sizes, int n_in,
                              void* d_out, int out_size, void* d_ws, size_t ws_size,
                              hipStream_t stream) {
    const float* ctx  = (const float*)d_in[0];   // [B,N,NODE]
    const float* W    = (const float*)d_in[1];   // [R,DEP,F]
    const int* heads  = (const int*)d_in[2];     // [B,L,E]
    const int* tails  = (const int*)d_in[3];
    const int* rels   = (const int*)d_in[4];
    const float* mask = (const float*)d_in[5];

    float* out = (float*)d_out;                  // [B,N,F]
    float* s   = (float*)d_ws;                   // [B,N,DEP] scatter sums
    float* c   = s + (size_t)B * NN * DEP;       // [B,N]     scatter counts

    int ws_count4 = (B * NN * DEP + B * NN) / 4; // float4 count to zero

    init_kernel<<<2048, 256, 0, stream>>>((const float4*)ctx, (float4*)out,
                                          (float4*)d_ws, ws_count4);

    for (int l = 0; l < L; ++l) {
        edge_kernel<<<B * E, 128, 0, stream>>>(W, heads, tails, rels, mask,
                                               out, s, c, l);
        node_kernel<<<B * NN, 128, 0, stream>>>(out, s, c);
    }
}